// Round 1
// baseline (407.644 us; speedup 1.0000x reference)
//
#include <hip/hip_runtime.h>
#include <cmath>

#define NB    128      // batches
#define DIM_  640
#define MM    100      // inner dim (K, unpadded)
#define KP    128      // K padded to MFMA multiple
#define LDK   136      // LDS row stride in halfs (128 + 8 pad -> conflict-free b128)

typedef _Float16 half8 __attribute__((ext_vector_type(8)));
typedef _Float16 half4_t __attribute__((ext_vector_type(4)));
typedef float f32x4 __attribute__((ext_vector_type(4)));

// ---------------------------------------------------------------- prep: d[b,i] = sum_m f16(x)^2
__global__ __launch_bounds__(256) void prep_d(const float* __restrict__ x,
                                              float* __restrict__ d) {
    const int row  = blockIdx.x * 4 + (threadIdx.x >> 6);   // 4 waves/block, 1 row/wave
    const int lane = threadIdx.x & 63;
    const float* xr = x + (size_t)row * MM;
    float a = (float)(_Float16)xr[lane];
    float s = a * a;
    if (lane < MM - 64) {
        float c = (float)(_Float16)xr[64 + lane];
        s += c * c;
    }
    #pragma unroll
    for (int off = 32; off; off >>= 1) s += __shfl_down(s, off, 64);
    if (lane == 0) d[row] = s;
}

// ---------------------------------------------------------------- stage 64 rows of x -> f16 LDS (zero-padded K)
__device__ inline void stage_tile(const float* __restrict__ src,  // x + (b*640 + tile*64)*100
                                  _Float16* lds, int tid) {
    // convert: 64 rows x 25 float4 chunks
    for (int c = tid; c < 64 * 25; c += 256) {
        const int row = c / 25;
        const int pos = c - row * 25;                 // float4 units
        const float4 v = *(const float4*)(src + (size_t)row * MM + pos * 4);
        half4_t h;
        h.x = (_Float16)v.x; h.y = (_Float16)v.y; h.z = (_Float16)v.z; h.w = (_Float16)v.w;
        *(half4_t*)(&lds[row * LDK + pos * 4]) = h;
    }
    // zero pad k = 100..127
    for (int i = tid; i < 64 * 28; i += 256) {
        const int row = i / 28;
        const int k = 100 + (i - row * 28);
        lds[row * LDK + k] = (_Float16)0.f;
    }
}

// ---------------------------------------------------------------- fused Gram+transform kernel
// MODE 0: accumulate row sums of dcov -> rowsum[b*640+i]
// MODE 1: write out = dcov - rm_i - rm_j + tot
template <int MODE>
__global__ __launch_bounds__(256, 4) void bdc_gemm(
        const float* __restrict__ x, const float* __restrict__ d,
        const float* __restrict__ t,
        float* __restrict__ rowsum,
        const float* __restrict__ rm, const float* __restrict__ tot,
        float* __restrict__ out) {
    __shared__ alignas(16) _Float16 As[64 * LDK];
    __shared__ alignas(16) _Float16 Bs[64 * LDK];
    __shared__ float rowacc[64];

    const int b   = blockIdx.y;
    const int it  = blockIdx.x;            // 64-row strip
    const int tid = threadIdx.x;
    const int wave = tid >> 6;
    const int lane = tid & 63;
    const int l16  = lane & 15;
    const int quad = lane >> 4;
    const int rowhalf = wave >> 1;         // waves in 2x2: rows 32 x cols 32 each
    const int colhalf = wave & 1;

    const float* xb = x + (size_t)b * DIM_ * MM;
    const float* db = d + b * DIM_;

    stage_tile(xb + (size_t)(it * 64) * MM, As, tid);
    if (MODE == 0 && tid < 64) rowacc[tid] = 0.f;

    const float expt = expf(t[0]);

    const int rbase = it * 64 + rowhalf * 32;
    float dr[2][4], rmr[2][4];
    #pragma unroll
    for (int ti = 0; ti < 2; ++ti)
        #pragma unroll
        for (int r = 0; r < 4; ++r) {
            const int gi = rbase + ti * 16 + quad * 4 + r;
            dr[ti][r] = db[gi];
            if (MODE == 1) rmr[ti][r] = rm[b * DIM_ + gi];
        }
    const float tb = (MODE == 1) ? tot[b] : 0.f;

    float rsum[2][4] = {};

    __syncthreads();   // As staged, rowacc init

    for (int jt = 0; jt < 10; ++jt) {
        if (jt) __syncthreads();           // previous Bs consumers done
        stage_tile(xb + (size_t)(jt * 64) * MM, Bs, tid);
        __syncthreads();

        f32x4 acc[2][2] = {};
        #pragma unroll
        for (int kk = 0; kk < 4; ++kk) {
            const int k = kk * 32 + quad * 8;
            half8 a0 = *(const half8*)(&As[(rowhalf * 32 + l16) * LDK + k]);
            half8 a1 = *(const half8*)(&As[(rowhalf * 32 + 16 + l16) * LDK + k]);
            half8 b0 = *(const half8*)(&Bs[(colhalf * 32 + l16) * LDK + k]);
            half8 b1 = *(const half8*)(&Bs[(colhalf * 32 + 16 + l16) * LDK + k]);
            acc[0][0] = __builtin_amdgcn_mfma_f32_16x16x32_f16(a0, b0, acc[0][0], 0, 0, 0);
            acc[0][1] = __builtin_amdgcn_mfma_f32_16x16x32_f16(a0, b1, acc[0][1], 0, 0, 0);
            acc[1][0] = __builtin_amdgcn_mfma_f32_16x16x32_f16(a1, b0, acc[1][0], 0, 0, 0);
            acc[1][1] = __builtin_amdgcn_mfma_f32_16x16x32_f16(a1, b1, acc[1][1], 0, 0, 0);
        }

        const int cbase = jt * 64 + colhalf * 32;
        const float dc[2]  = { db[cbase + l16], db[cbase + 16 + l16] };
        float rmc[2];
        if (MODE == 1) {
            rmc[0] = rm[b * DIM_ + cbase + l16];
            rmc[1] = rm[b * DIM_ + cbase + 16 + l16];
        }

        #pragma unroll
        for (int ti = 0; ti < 2; ++ti) {
            #pragma unroll
            for (int r = 0; r < 4; ++r) {
                const int gi = rbase + ti * 16 + quad * 4 + r;
                float v[2];
                #pragma unroll
                for (int tj = 0; tj < 2; ++tj) {
                    const int gj = cbase + tj * 16 + l16;
                    float raw = dr[ti][r] + dc[tj] - 2.0f * acc[ti][tj][r];
                    raw = (gi == gj) ? 1e-4f : fmaxf(raw, 1e-4f);
                    v[tj] = sqrtf(expt * raw + 1e-5f);
                }
                if (MODE == 0) {
                    float s = v[0] + v[1];
                    s += __shfl_xor(s, 1, 64);
                    s += __shfl_xor(s, 2, 64);
                    s += __shfl_xor(s, 4, 64);
                    s += __shfl_xor(s, 8, 64);   // sum over the 16 cols of this quad-group
                    rsum[ti][r] += s;
                } else {
                    float* orow = out + (size_t)b * DIM_ * DIM_ + (size_t)gi * DIM_;
                    orow[cbase + l16]      = v[0] - rmr[ti][r] - rmc[0] + tb;
                    orow[cbase + 16 + l16] = v[1] - rmr[ti][r] - rmc[1] + tb;
                }
            }
        }
    }

    if (MODE == 0) {
        if (l16 == 0) {   // one lane per (quad, wave) holds the group sums
            #pragma unroll
            for (int ti = 0; ti < 2; ++ti)
                #pragma unroll
                for (int r = 0; r < 4; ++r)
                    atomicAdd(&rowacc[rowhalf * 32 + ti * 16 + quad * 4 + r], rsum[ti][r]);
        }
        __syncthreads();
        if (tid < 64) rowsum[b * DIM_ + it * 64 + tid] = rowacc[tid];
    }
}

// ---------------------------------------------------------------- per-batch means
__global__ __launch_bounds__(256) void bdc_tot(const float* __restrict__ rowsum,
                                               float* __restrict__ rm,
                                               float* __restrict__ tot) {
    const int b = blockIdx.x, tid = threadIdx.x;
    const float* rs = rowsum + b * DIM_;
    const float v0 = rs[tid];
    const float v1 = rs[tid + 256];
    const float v2 = (tid < 128) ? rs[tid + 512] : 0.f;
    __shared__ float red[256];
    red[tid] = v0 + v1 + v2;
    __syncthreads();
    for (int off = 128; off; off >>= 1) {
        if (tid < off) red[tid] += red[tid + off];
        __syncthreads();
    }
    const float inv = 1.0f / 640.0f;
    rm[b * DIM_ + tid]       = v0 * inv;
    rm[b * DIM_ + 256 + tid] = v1 * inv;
    if (tid < 128) rm[b * DIM_ + 512 + tid] = v2 * inv;
    if (tid == 0) tot[b] = red[0] / (640.0f * 640.0f);
}

// ---------------------------------------------------------------- launch
extern "C" void kernel_launch(void* const* d_in, const int* in_sizes, int n_in,
                              void* d_out, int out_size, void* d_ws, size_t ws_size,
                              hipStream_t stream) {
    const float* x = (const float*)d_in[0];
    const float* t = (const float*)d_in[1];
    float* out = (float*)d_out;

    char* ws = (char*)d_ws;
    float* d      = (float*)(ws);                         // 128*640*4 = 327,680 B
    float* rowsum = (float*)(ws + 327680);                // 327,680 B
    float* rm     = (float*)(ws + 2 * 327680);            // 327,680 B
    float* tot    = (float*)(ws + 3 * 327680);            // 512 B

    prep_d<<<dim3((NB * DIM_) / 4), dim3(256), 0, stream>>>(x, d);
    bdc_gemm<0><<<dim3(10, NB), dim3(256), 0, stream>>>(x, d, t, rowsum, nullptr, nullptr, nullptr);
    bdc_tot<<<dim3(NB), dim3(256), 0, stream>>>(rowsum, rm, tot);
    bdc_gemm<1><<<dim3(10, NB), dim3(256), 0, stream>>>(x, d, t, nullptr, rm, tot, out);
}

// Round 2
// 345.493 us; speedup vs baseline: 1.1799x; 1.1799x over previous
//
#include <hip/hip_runtime.h>
#include <cmath>

#define NB    128      // batches
#define DIM_  640
#define MM    100      // inner dim (K, unpadded)
#define LDK   136      // LDS row stride in halfs (128 + 8 pad)
#define TS    72       // LDS transpose-tile row stride in halfs (64 + 8 pad)

typedef _Float16 half8 __attribute__((ext_vector_type(8)));
typedef _Float16 half4_t __attribute__((ext_vector_type(4)));
typedef float f32x4 __attribute__((ext_vector_type(4)));

// ---------------------------------------------------------------- prep: d[b,i] = sum_m f16(x)^2 ; also zero rowsum
__global__ __launch_bounds__(256) void prep_d(const float* __restrict__ x,
                                              float* __restrict__ d,
                                              float* __restrict__ rowsum) {
    if (blockIdx.x < (NB * DIM_) / 256)    // 320 blocks zero the 81920-float rowsum
        rowsum[blockIdx.x * 256 + threadIdx.x] = 0.f;
    const int row  = blockIdx.x * 4 + (threadIdx.x >> 6);   // 4 waves/block, 1 row/wave
    const int lane = threadIdx.x & 63;
    const float* xr = x + (size_t)row * MM;
    float a = (float)(_Float16)xr[lane];
    float s = a * a;
    if (lane < MM - 64) {
        float c = (float)(_Float16)xr[64 + lane];
        s += c * c;
    }
    #pragma unroll
    for (int off = 32; off; off >>= 1) s += __shfl_down(s, off, 64);
    if (lane == 0) d[row] = s;
}

// ---------------------------------------------------------------- stage 64 rows of x -> f16 LDS (zero-padded K)
__device__ inline void stage_tile(const float* __restrict__ src,
                                  _Float16* lds, int tid) {
    for (int c = tid; c < 64 * 25; c += 256) {
        const int row = c / 25;
        const int pos = c - row * 25;                 // float4 units
        const float4 v = *(const float4*)(src + (size_t)row * MM + pos * 4);
        half4_t h;
        h.x = (_Float16)v.x; h.y = (_Float16)v.y; h.z = (_Float16)v.z; h.w = (_Float16)v.w;
        *(half4_t*)(&lds[row * LDK + pos * 4]) = h;
    }
    for (int i = tid; i < 64 * 28; i += 256) {        // zero pad k = 100..127
        const int row = i / 28;
        const int k = 100 + (i - row * 28);
        lds[row * LDK + k] = (_Float16)0.f;
    }
}

// ---------------------------------------------------------------- pass 1: one block per (batch, tile-pair it<=jt)
// computes 64x64 dcov tile, stores f16 tile (and transpose) to dc, accumulates row sums
__global__ __launch_bounds__(256) void bdc_pass1(
        const float* __restrict__ x, const float* __restrict__ d,
        const float* __restrict__ t,
        float* __restrict__ rowsum, _Float16* __restrict__ dc) {
    __shared__ alignas(16) _Float16 As[64 * LDK];
    __shared__ alignas(16) _Float16 Bs[64 * LDK];
    __shared__ float rowacc[64];
    __shared__ float colacc[64];
    _Float16* T = As;                       // transpose tile aliases As (dead after MFMA)

    const int b   = blockIdx.y;
    const int p   = blockIdx.x;             // 0..54 -> (it, jt), it <= jt
    int it = 0, rem = p;
    while (rem >= 10 - it) { rem -= 10 - it; ++it; }
    const int jt = it + rem;
    const bool diag = (it == jt);

    const int tid = threadIdx.x;
    const int wave = tid >> 6;
    const int lane = tid & 63;
    const int l16  = lane & 15;
    const int quad = lane >> 4;
    const int rowhalf = wave >> 1;          // 2x2 wave grid over the 64x64 tile
    const int colhalf = wave & 1;

    const float* xb = x + (size_t)b * DIM_ * MM;
    const float* db = d + b * DIM_;

    stage_tile(xb + (size_t)(it * 64) * MM, As, tid);
    if (!diag) stage_tile(xb + (size_t)(jt * 64) * MM, Bs, tid);
    if (tid < 64)  rowacc[tid] = 0.f;
    else if (tid < 128) colacc[tid - 64] = 0.f;

    const float expt = expf(t[0]);
    const int rbase = it * 64 + rowhalf * 32;
    const int cbase = jt * 64 + colhalf * 32;
    float dr[2][4];
    #pragma unroll
    for (int ti = 0; ti < 2; ++ti)
        #pragma unroll
        for (int r = 0; r < 4; ++r)
            dr[ti][r] = db[rbase + ti * 16 + quad * 4 + r];
    const float dcv[2] = { db[cbase + l16], db[cbase + 16 + l16] };

    __syncthreads();

    const _Float16* Bp = diag ? As : Bs;
    f32x4 acc[2][2] = {};
    #pragma unroll
    for (int kk = 0; kk < 4; ++kk) {
        const int k = kk * 32 + quad * 8;
        half8 a0 = *(const half8*)(&As[(rowhalf * 32 + l16) * LDK + k]);
        half8 a1 = *(const half8*)(&As[(rowhalf * 32 + 16 + l16) * LDK + k]);
        half8 b0 = *(const half8*)(&Bp[(colhalf * 32 + l16) * LDK + k]);
        half8 b1 = *(const half8*)(&Bp[(colhalf * 32 + 16 + l16) * LDK + k]);
        acc[0][0] = __builtin_amdgcn_mfma_f32_16x16x32_f16(a0, b0, acc[0][0], 0, 0, 0);
        acc[0][1] = __builtin_amdgcn_mfma_f32_16x16x32_f16(a0, b1, acc[0][1], 0, 0, 0);
        acc[1][0] = __builtin_amdgcn_mfma_f32_16x16x32_f16(a1, b0, acc[1][0], 0, 0, 0);
        acc[1][1] = __builtin_amdgcn_mfma_f32_16x16x32_f16(a1, b1, acc[1][1], 0, 0, 0);
    }

    // ---- epilogue: dcov values + row/col partial sums (registers)
    float v[2][4][2];
    float cp0 = 0.f, cp1 = 0.f;
    #pragma unroll
    for (int ti = 0; ti < 2; ++ti) {
        #pragma unroll
        for (int r = 0; r < 4; ++r) {
            const int gi = rbase + ti * 16 + quad * 4 + r;
            #pragma unroll
            for (int tj = 0; tj < 2; ++tj) {
                const int gj = cbase + tj * 16 + l16;
                float raw = dr[ti][r] + dcv[tj] - 2.0f * acc[ti][tj][r];
                raw = (gi == gj) ? 1e-4f : fmaxf(raw, 1e-4f);
                v[ti][r][tj] = sqrtf(expt * raw + 1e-5f);
            }
            cp0 += v[ti][r][0];
            cp1 += v[ti][r][1];
            float s = v[ti][r][0] + v[ti][r][1];
            s += __shfl_xor(s, 1, 64);
            s += __shfl_xor(s, 2, 64);
            s += __shfl_xor(s, 4, 64);
            s += __shfl_xor(s, 8, 64);
            if (l16 == 0)
                atomicAdd(&rowacc[rowhalf * 32 + ti * 16 + quad * 4 + r], s);
        }
    }
    cp0 += __shfl_xor(cp0, 16, 64); cp0 += __shfl_xor(cp0, 32, 64);
    cp1 += __shfl_xor(cp1, 16, 64); cp1 += __shfl_xor(cp1, 32, 64);
    if (quad == 0) {
        atomicAdd(&colacc[colhalf * 32 + l16],      cp0);
        atomicAdd(&colacc[colhalf * 32 + 16 + l16], cp1);
    }

    __syncthreads();   // all frag reads done -> safe to overwrite As with T

    #pragma unroll
    for (int ti = 0; ti < 2; ++ti)
        #pragma unroll
        for (int r = 0; r < 4; ++r) {
            const int ri = rowhalf * 32 + ti * 16 + quad * 4 + r;
            T[ri * TS + colhalf * 32 + l16]      = (_Float16)v[ti][r][0];
            T[ri * TS + colhalf * 32 + 16 + l16] = (_Float16)v[ti][r][1];
        }

    __syncthreads();

    // ---- coalesced global stores of the f16 tile (and its transpose)
    #pragma unroll
    for (int w = tid; w < 512; w += 256) {
        const int r2 = w >> 3;
        const int c2 = (w & 7) * 8;
        half8 h = *(const half8*)(&T[r2 * TS + c2]);
        *(half8*)(dc + ((size_t)(b * DIM_ + it * 64 + r2)) * DIM_ + jt * 64 + c2) = h;
        if (!diag) {
            half8 ht;
            #pragma unroll
            for (int k = 0; k < 8; ++k) ht[k] = T[(c2 + k) * TS + r2];
            *(half8*)(dc + ((size_t)(b * DIM_ + jt * 64 + r2)) * DIM_ + it * 64 + c2) = ht;
        }
    }

    if (tid < 64) {
        atomicAdd(&rowsum[b * DIM_ + it * 64 + tid], rowacc[tid]);
        if (!diag) atomicAdd(&rowsum[b * DIM_ + jt * 64 + tid], colacc[tid]);
    }
}

// ---------------------------------------------------------------- per-batch means
__global__ __launch_bounds__(256) void bdc_tot(const float* __restrict__ rowsum,
                                               float* __restrict__ rm,
                                               float* __restrict__ tot) {
    const int b = blockIdx.x, tid = threadIdx.x;
    const float* rs = rowsum + b * DIM_;
    const float v0 = rs[tid];
    const float v1 = rs[tid + 256];
    const float v2 = (tid < 128) ? rs[tid + 512] : 0.f;
    __shared__ float red[256];
    red[tid] = v0 + v1 + v2;
    __syncthreads();
    for (int off = 128; off; off >>= 1) {
        if (tid < off) red[tid] += red[tid + off];
        __syncthreads();
    }
    const float inv = 1.0f / 640.0f;
    rm[b * DIM_ + tid]       = v0 * inv;
    rm[b * DIM_ + 256 + tid] = v1 * inv;
    if (tid < 128) rm[b * DIM_ + 512 + tid] = v2 * inv;
    if (tid == 0) tot[b] = red[0] / (640.0f * 640.0f);
}

// ---------------------------------------------------------------- pass 3: out = f32(dcov) - rm_i - rm_j + tot
__global__ __launch_bounds__(256) void bdc_center(const _Float16* __restrict__ dc,
                                                  const float* __restrict__ rm,
                                                  const float* __restrict__ tot,
                                                  float* __restrict__ out) {
    const unsigned L  = blockIdx.x * 256 + threadIdx.x;   // half8 chunk id, 6,553,600 total
    const unsigned j8 = L % 80u;
    const unsigned ib = L / 80u;          // b*640 + i
    const unsigned b  = ib / 640u;
    half8 h = *(const half8*)(dc + (size_t)L * 8);
    const float c = tot[b] - rm[ib];
    const float* rmj = rm + b * 640u + j8 * 8u;
    const float4 ra = *(const float4*)rmj;
    const float4 rb = *(const float4*)(rmj + 4);
    float4 o0, o1;
    o0.x = (float)h[0] - ra.x + c;  o0.y = (float)h[1] - ra.y + c;
    o0.z = (float)h[2] - ra.z + c;  o0.w = (float)h[3] - ra.w + c;
    o1.x = (float)h[4] - rb.x + c;  o1.y = (float)h[5] - rb.y + c;
    o1.z = (float)h[6] - rb.z + c;  o1.w = (float)h[7] - rb.w + c;
    float4* op = (float4*)(out + (size_t)L * 8);
    op[0] = o0; op[1] = o1;
}

// ---------------------------------------------------------------- launch
extern "C" void kernel_launch(void* const* d_in, const int* in_sizes, int n_in,
                              void* d_out, int out_size, void* d_ws, size_t ws_size,
                              hipStream_t stream) {
    const float* x = (const float*)d_in[0];
    const float* t = (const float*)d_in[1];
    float* out = (float*)d_out;

    char* ws = (char*)d_ws;
    float*     d      = (float*)(ws);                      // 327,680 B
    float*     rowsum = (float*)(ws + 327680);             // 327,680 B
    float*     rm     = (float*)(ws + 2 * 327680);         // 327,680 B
    float*     tot    = (float*)(ws + 3 * 327680);         // 512 B
    _Float16*  dc     = (_Float16*)(ws + 3 * 327680 + 512);// 104,857,600 B

    prep_d<<<dim3((NB * DIM_) / 4), dim3(256), 0, stream>>>(x, d, rowsum);
    bdc_pass1<<<dim3(55, NB), dim3(256), 0, stream>>>(x, d, t, rowsum, dc);
    bdc_tot<<<dim3(NB), dim3(256), 0, stream>>>(rowsum, rm, tot);
    bdc_center<<<dim3(25600), dim3(256), 0, stream>>>(dc, rm, tot, out);
}